// Round 1
// baseline (832.936 us; speedup 1.0000x reference)
//
#include <hip/hip_runtime.h>
#include <cstdint>
#include <cstddef>

// Problem constants (from reference)
#define OUT_F 4096
#define IN_F  11008
#define VECD  8
#define NVEC  (OUT_F * IN_F / VECD)   // 5,636,096 vectors
#define VPR   (IN_F / VECD)           // 1376 vectors per output row
#define M_DIM 4096                    // 2*2048 flattened batch*seq
#define N_DIM OUT_F
#define K_DIM IN_F

typedef __attribute__((ext_vector_type(4))) float f32x4;
typedef __attribute__((ext_vector_type(8))) __bf16 bf16x8;
typedef __attribute__((ext_vector_type(4))) unsigned int u32x4;

__device__ inline unsigned short f2bf(float f) {
  union { float f; unsigned int u; } v; v.f = f;
  unsigned int u = v.u;
  unsigned int r = u + 0x7FFFu + ((u >> 16) & 1u);   // RNE
  return (unsigned short)(r >> 16);
}

// ---------------------------------------------------------------------------
// Phase 1: dequantize W (codebook gather * row scale) -> bf16, cast X -> bf16.
// One thread per 8-element vector: reads 4B index + 32B codebook (L2-resident,
// codebook is 1 MB) + 32B of x; writes 16B of W-bf16 + 16B of X-bf16.
// ---------------------------------------------------------------------------
__global__ __launch_bounds__(256) void dequant_cast_kernel(
    const float* __restrict__ x, const int* __restrict__ indices,
    const float* __restrict__ cb, const float* __restrict__ scales,
    unsigned short* __restrict__ xb, unsigned short* __restrict__ wb) {
  int v = blockIdx.x * 256 + threadIdx.x;
  if (v >= NVEC) return;

  int id = indices[v];
  int o  = v / VPR;                    // output row (magic-mul divide)
  float s = scales[o];

  const f32x4* c = (const f32x4*)(cb + (size_t)id * VECD);
  f32x4 c0 = c[0], c1 = c[1];
  u32x4 w;
  w.x = (unsigned)f2bf(c0.x * s) | ((unsigned)f2bf(c0.y * s) << 16);
  w.y = (unsigned)f2bf(c0.z * s) | ((unsigned)f2bf(c0.w * s) << 16);
  w.z = (unsigned)f2bf(c1.x * s) | ((unsigned)f2bf(c1.y * s) << 16);
  w.w = (unsigned)f2bf(c1.z * s) | ((unsigned)f2bf(c1.w * s) << 16);
  *(u32x4*)(wb + (size_t)v * 8) = w;

  const f32x4* xp = (const f32x4*)(x + (size_t)v * 8);
  f32x4 x0 = xp[0], x1 = xp[1];
  u32x4 q;
  q.x = (unsigned)f2bf(x0.x) | ((unsigned)f2bf(x0.y) << 16);
  q.y = (unsigned)f2bf(x0.z) | ((unsigned)f2bf(x0.w) << 16);
  q.z = (unsigned)f2bf(x1.x) | ((unsigned)f2bf(x1.y) << 16);
  q.w = (unsigned)f2bf(x1.z) | ((unsigned)f2bf(x1.w) << 16);
  *(u32x4*)(xb + (size_t)v * 8) = q;
}

// ---------------------------------------------------------------------------
// Phase 2: C[M,N] = A[M,K] * B[N,K]^T  (both bf16, K-contiguous; fp32 out)
// m97-ladder structure: 128x128 block tile, 4 waves in 2x2, each wave a 4x4
// grid of 16x16x32 bf16 MFMAs. Single-buffered 16 KB LDS, global_load_lds
// width=16 staging (LDS layout == lane order: NO padding), 2-barrier K-loop.
// ---------------------------------------------------------------------------
#define GLD16(g, l)                                                     \
  __builtin_amdgcn_global_load_lds(                                     \
      (const __attribute__((address_space(1))) void*)(g),               \
      (__attribute__((address_space(3))) void*)(l), 16, 0, 0)

__global__ __launch_bounds__(256) void gemm_bt_kernel(
    const unsigned short* __restrict__ A,   // M x K bf16 (X)
    const unsigned short* __restrict__ B,   // N x K bf16 (W)
    float* __restrict__ C) {                // M x N fp32
  __shared__ unsigned short As[128 * 32];   // 8 KB
  __shared__ unsigned short Bs[128 * 32];   // 8 KB

  const int tid  = threadIdx.x;
  const int bm   = blockIdx.x >> 5;         // 0..31
  const int bn   = blockIdx.x & 31;         // 0..31
  const int lane = tid & 63;
  const int wave = tid >> 6;
  const int wm   = (wave & 1) * 64;
  const int wn   = (wave >> 1) * 64;
  const int lrow = lane & 15;               // m (A-frag) / n (B-frag) index
  const int kgrp = lane >> 4;               // k-group: k = kgrp*8 .. +8

  // Staging map: thread t loads 8 bf16 (16B); linear elem e = t*8 (+2048 for
  // second issue). Row = e/32, col = e%32 -> LDS is exact row-major 128x32.
  const int srow = tid >> 2;                // 0..63
  const int scol = (tid & 3) * 8;           // 0,8,16,24
  const unsigned short* a0 = A + (size_t)(bm * 128 + srow) * K_DIM + scol;
  const unsigned short* a1 = a0 + (size_t)64 * K_DIM;
  const unsigned short* b0 = B + (size_t)(bn * 128 + srow) * K_DIM + scol;
  const unsigned short* b1 = b0 + (size_t)64 * K_DIM;
  unsigned short* lA0 = &As[tid * 8];
  unsigned short* lA1 = &As[2048 + tid * 8];
  unsigned short* lB0 = &Bs[tid * 8];
  unsigned short* lB1 = &Bs[2048 + tid * 8];

  f32x4 acc[4][4];
#pragma unroll
  for (int i = 0; i < 4; i++)
#pragma unroll
    for (int j = 0; j < 4; j++) acc[i][j] = f32x4{0.f, 0.f, 0.f, 0.f};

  for (int k0 = 0; k0 < K_DIM; k0 += 32) {
    __syncthreads();                        // protect LDS from overwrite
    GLD16(a0, lA0); GLD16(a1, lA1);
    GLD16(b0, lB0); GLD16(b1, lB1);
    a0 += 32; a1 += 32; b0 += 32; b1 += 32;
    __syncthreads();                        // drains vmcnt(0) then s_barrier

    bf16x8 af[4], bfr[4];
#pragma unroll
    for (int i = 0; i < 4; i++)
      af[i] = *(const bf16x8*)&As[(wm + i * 16 + lrow) * 32 + kgrp * 8];
#pragma unroll
    for (int j = 0; j < 4; j++)
      bfr[j] = *(const bf16x8*)&Bs[(wn + j * 16 + lrow) * 32 + kgrp * 8];

#pragma unroll
    for (int i = 0; i < 4; i++)
#pragma unroll
      for (int j = 0; j < 4; j++)
        acc[i][j] = __builtin_amdgcn_mfma_f32_16x16x32_bf16(
            af[i], bfr[j], acc[i][j], 0, 0, 0);
  }

  // Epilogue: C/D layout col = lane&15, row = (lane>>4)*4 + reg  [m89-verified]
#pragma unroll
  for (int i = 0; i < 4; i++) {
    const int row0 = bm * 128 + wm + i * 16 + kgrp * 4;
#pragma unroll
    for (int j = 0; j < 4; j++) {
      const int col = bn * 128 + wn + j * 16 + lrow;
#pragma unroll
      for (int r = 0; r < 4; r++)
        C[(size_t)(row0 + r) * N_DIM + col] = acc[i][j][r];
    }
  }
}

// ---------------------------------------------------------------------------
// Fallback (only if workspace is too small for the bf16 operands): naive
// fp32 dequant+dot. Correct but slow; should never trigger with a normal ws.
// ---------------------------------------------------------------------------
__global__ __launch_bounds__(256) void naive_kernel(
    const float* __restrict__ x, const int* __restrict__ indices,
    const float* __restrict__ cb, const float* __restrict__ scales,
    float* __restrict__ out) {
  int n = blockIdx.x * 256 + threadIdx.x;
  int m = blockIdx.y;
  if (n >= N_DIM) return;
  float s = scales[n];
  const float* xr = x + (size_t)m * IN_F;
  const int* ir = indices + (size_t)n * VPR;
  float acc = 0.f;
  for (int v = 0; v < VPR; v++) {
    int id = ir[v];
    const float* c = cb + (size_t)id * 8;
#pragma unroll
    for (int e = 0; e < 8; e++) acc += xr[v * 8 + e] * c[e];
  }
  out[(size_t)m * N_DIM + n] = acc * s;
}

extern "C" void kernel_launch(void* const* d_in, const int* in_sizes, int n_in,
                              void* d_out, int out_size, void* d_ws, size_t ws_size,
                              hipStream_t stream) {
  const float* x       = (const float*)d_in[0];   // (2,2048,11008) fp32
  const int*   indices = (const int*)d_in[1];     // (5636096,) int32
  const float* cb      = (const float*)d_in[2];   // (32768,8) fp32
  const float* scales  = (const float*)d_in[3];   // (4096,1) fp32
  float* out = (float*)d_out;                     // (2,2048,4096) fp32

  const size_t xb_elems = (size_t)M_DIM * K_DIM;  // 45,088,768
  const size_t wb_elems = (size_t)N_DIM * K_DIM;  // 45,088,768
  const size_t need = (xb_elems + wb_elems) * sizeof(unsigned short); // ~172 MB

  if (ws_size >= need) {
    unsigned short* xb = (unsigned short*)d_ws;
    unsigned short* wb = xb + xb_elems;
    dequant_cast_kernel<<<NVEC / 256, 256, 0, stream>>>(x, indices, cb, scales,
                                                        xb, wb);
    gemm_bt_kernel<<<(M_DIM / 128) * (N_DIM / 128), 256, 0, stream>>>(xb, wb,
                                                                      out);
  } else {
    naive_kernel<<<dim3(N_DIM / 256, M_DIM), 256, 0, stream>>>(x, indices, cb,
                                                               scales, out);
  }
}